// Round 3
// baseline (217.787 us; speedup 1.0000x reference)
//
#include <hip/hip_runtime.h>
#include <hip/hip_cooperative_groups.h>

namespace cg = cooperative_groups;

#define NBINS 256
#define GBLK  512   // 2 blocks/CU, co-resident (cooperative)
#define TPB   256

__device__ __forceinline__ float fs_val(int j) {
    // floating_space[j] = clip(float32(j) * float32(1/255), 0, 1)
    const float c = (float)(1.0 / 255.0);
    float v = (float)j * c;
    return v > 1.0f ? 1.0f : v;
}

__device__ __forceinline__ int bin_of(float s) {
    int i = (int)(s * 256.0f);           // truncation toward zero, s >= 0
    i = i < 0 ? 0 : i;
    i = i > NBINS - 1 ? NBINS - 1 : i;
    return i;
}

// Single cooperative kernel: hist -> (grid sync) -> per-block cdf+map -> apply.
__global__ void __launch_bounds__(TPB, 2)
hm_all(const float* __restrict__ src, const float* __restrict__ tgt,
       int* __restrict__ hist /* 512 ints: S then T */,
       float* __restrict__ out, int nquad)
{
    cg::grid_group grid = cg::this_grid();

    __shared__ int   hs[NBINS];
    __shared__ int   ht[NBINS];
    __shared__ float cdfT[NBINS];
    __shared__ float pm[NBINS];

    const int t    = threadIdx.x;          // blockDim.x == 256 == NBINS
    const int gtid = blockIdx.x * TPB + t;
    const int nth  = GBLK * TPB;
    const float c1 = (float)(127.0 / 255.0);

    // ---- phase 0: zero global hist at the device-coherent point ----
    if (gtid < 2 * NBINS) {
        __hip_atomic_store(&hist[gtid], 0, __ATOMIC_RELAXED, __HIP_MEMORY_SCOPE_AGENT);
    }
    hs[t] = 0; ht[t] = 0;
    grid.sync();   // zeroing visible to all before any atomicAdd

    // ---- phase 1: both histograms in LDS, one pass over src & tgt ----
    for (int q = gtid; q < nquad; q += nth) {
        const float4* s4 = (const float4*)(src + 12 * (size_t)q);
        float4 a = s4[0], b = s4[1], c = s4[2];
        // channel-0 of the 4 pixels: offsets 0,3,6,9
        atomicAdd(&hs[bin_of((a.x + 1.0f) * c1)], 1);
        atomicAdd(&hs[bin_of((a.w + 1.0f) * c1)], 1);
        atomicAdd(&hs[bin_of((b.z + 1.0f) * c1)], 1);
        atomicAdd(&hs[bin_of((c.y + 1.0f) * c1)], 1);

        const float4* t4 = (const float4*)(tgt + 12 * (size_t)q);
        float4 ta = t4[0], tb = t4[1], tc = t4[2];
        {
            float r = (ta.x + 1.0f) * c1, g = (ta.y + 1.0f) * c1, bb = (ta.z + 1.0f) * c1;
            atomicAdd(&ht[bin_of(r * 0.299f + g * 0.587f + bb * 0.114f)], 1);
        }
        {
            float r = (ta.w + 1.0f) * c1, g = (tb.x + 1.0f) * c1, bb = (tb.y + 1.0f) * c1;
            atomicAdd(&ht[bin_of(r * 0.299f + g * 0.587f + bb * 0.114f)], 1);
        }
        {
            float r = (tb.z + 1.0f) * c1, g = (tb.w + 1.0f) * c1, bb = (tc.x + 1.0f) * c1;
            atomicAdd(&ht[bin_of(r * 0.299f + g * 0.587f + bb * 0.114f)], 1);
        }
        {
            float r = (tc.y + 1.0f) * c1, g = (tc.z + 1.0f) * c1, bb = (tc.w + 1.0f) * c1;
            atomicAdd(&ht[bin_of(r * 0.299f + g * 0.587f + bb * 0.114f)], 1);
        }
    }
    __syncthreads();
    // flush block-local hists (device-scope atomics, 512 addresses)
    atomicAdd(&hist[t], hs[t]);
    atomicAdd(&hist[NBINS + t], ht[t]);
    grid.sync();   // all counts final & visible

    // ---- phase 2: EVERY block redundantly computes cdf + pxmap in LDS ----
    {
        int vS = __hip_atomic_load(&hist[t],         __ATOMIC_ACQUIRE, __HIP_MEMORY_SCOPE_AGENT);
        int vT = __hip_atomic_load(&hist[NBINS + t], __ATOMIC_ACQUIRE, __HIP_MEMORY_SCOPE_AGENT);
        hs[t] = vS; ht[t] = vT;
        __syncthreads();
        // Hillis-Steele inclusive scan over 256 bins
        for (int off = 1; off < NBINS; off <<= 1) {
            int aS = (t >= off) ? hs[t - off] : 0;
            int aT = (t >= off) ? ht[t - off] : 0;
            __syncthreads();
            hs[t] += aS; ht[t] += aT;
            __syncthreads();
        }
        int minS = hs[0], minT = ht[0];   // cdf_min == cdf[0] (nondecreasing)
        float denomN = (float)(4 * nquad - 1);
        float xS = (float)(hs[t] - minS) / denomN;   // cdfsrc[t]
        cdfT[t]  = (float)(ht[t] - minT) / denomN;   // cdftgt[t]
        __syncthreads();

        // interpolate(dx=cdftgt, dy=floating_space, x=cdfsrc[t]) -> pm[t]
        float res;
        if (xS <= cdfT[0]) {
            res = fs_val(0);
        } else if (xS >= cdfT[NBINS - 1]) {
            res = fs_val(NBINS - 1);
        } else {
            // first j with cdfT[j] > xS ; here cdfT[0] < xS < cdfT[255]
            int lo = 0, hi = NBINS - 1;
            while (hi - lo > 1) {
                int mid = (lo + hi) >> 1;
                if (cdfT[mid] > xS) hi = mid; else lo = mid;
            }
            int j1 = hi, j0 = hi - 1;
            float dx0 = cdfT[j0], dx1 = cdfT[j1];
            float dy0 = fs_val(j0), dy1 = fs_val(j1);
            res = dy0 + (dy1 - dy0) * (xS - dx0) / (dx1 - dx0);  // dx1 > xS >= dx0
        }
        pm[t] = res;
        __syncthreads();
    }

    // ---- phase 3: map every src pixel through pm (src re-read, LLC-warm) ----
    const float c2 = (float)(255.0 / 127.0);
    for (int q = gtid; q < nquad; q += nth) {
        const float4* s4 = (const float4*)(src + 12 * (size_t)q);
        float4 a = s4[0], b = s4[1], c = s4[2];
        float xv[4] = {a.x, a.w, b.z, c.y};
        float ov[4];
        #pragma unroll
        for (int k = 0; k < 4; ++k) {
            float x = (xv[k] + 1.0f) * c1;
            float r;
            if (x <= 0.0f) {
                r = pm[0];
            } else if (x >= 1.0f) {
                r = pm[NBINS - 1];
            } else {
                // first j with fs[j] > x : guess + fixup to match exact float compares
                int g = (int)(x * 255.0f) + 1;
                g = g < 1 ? 1 : (g > NBINS - 1 ? NBINS - 1 : g);
                while (g < NBINS - 1 && fs_val(g) <= x) ++g;
                while (g > 1 && fs_val(g - 1) > x) --g;
                int j1 = g, j0 = g - 1;
                float dx0 = fs_val(j0), dx1 = fs_val(j1);
                r = pm[j0] + (pm[j1] - pm[j0]) * (x - dx0) / (dx1 - dx0);
            }
            r = r < 0.0f ? 0.0f : (r > 1.0f ? 1.0f : r);
            ov[k] = r * c2 - 1.0f;
        }
        float4 o;
        o.x = ov[0]; o.y = ov[1]; o.z = ov[2]; o.w = ov[3];
        ((float4*)out)[q] = o;
    }
}

extern "C" void kernel_launch(void* const* d_in, const int* in_sizes, int n_in,
                              void* d_out, int out_size, void* d_ws, size_t ws_size,
                              hipStream_t stream) {
    const float* src = (const float*)d_in[0];
    const float* tgt = (const float*)d_in[1];
    float* out = (float*)d_out;

    int nquad = out_size >> 2;        // 1024*1024/4
    int* hist = (int*)d_ws;           // 512 ints

    void* kargs[] = { (void*)&src, (void*)&tgt, (void*)&hist, (void*)&out, (void*)&nquad };
    hipLaunchCooperativeKernel((void*)hm_all, dim3(GBLK), dim3(TPB), kargs, 0, stream);
}

// Round 4
// 92.049 us; speedup vs baseline: 2.3660x; 2.3660x over previous
//
#include <hip/hip_runtime.h>

#define NBINS 256
#define HBLK  512   // histogram blocks (2 per CU)
#define TPB   256

__device__ __forceinline__ float fs_val(int j) {
    // floating_space[j] = clip(float32(j) * float32(1/255), 0, 1)
    const float c = (float)(1.0 / 255.0);
    float v = (float)j * c;
    return v > 1.0f ? 1.0f : v;
}

__device__ __forceinline__ int bin_of(float s) {
    int i = (int)(s * 256.0f);           // truncation toward zero, s >= 0
    i = i < 0 ? 0 : i;
    i = i > NBINS - 1 ? NBINS - 1 : i;
    return i;
}

// Kernel 1: both histograms (LDS + device-atomic flush); the LAST block to
// finish also computes the CDFs + first interpolation and writes pxmap.
__global__ void __launch_bounds__(TPB)
hm_hist_cdf(const float* __restrict__ src, const float* __restrict__ tgt,
            int* __restrict__ hist /* 512 ints */, int* __restrict__ counter,
            float* __restrict__ pxmap, int nquad) {
    __shared__ int hs[NBINS];
    __shared__ int ht[NBINS];
    __shared__ float cdfT[NBINS];
    __shared__ int lastFlag;

    const int t = threadIdx.x;               // TPB == NBINS == 256
    hs[t] = 0; ht[t] = 0;
    __syncthreads();

    const float c1 = (float)(127.0 / 255.0);
    int tid = blockIdx.x * TPB + t;
    int stride = gridDim.x * TPB;

    for (int q = tid; q < nquad; q += stride) {
        const float4* s4 = (const float4*)(src + 12 * (size_t)q);
        float4 a = s4[0], b = s4[1], c = s4[2];
        // channel-0 of the 4 pixels: offsets 0,3,6,9
        atomicAdd(&hs[bin_of((a.x + 1.0f) * c1)], 1);
        atomicAdd(&hs[bin_of((a.w + 1.0f) * c1)], 1);
        atomicAdd(&hs[bin_of((b.z + 1.0f) * c1)], 1);
        atomicAdd(&hs[bin_of((c.y + 1.0f) * c1)], 1);

        const float4* t4 = (const float4*)(tgt + 12 * (size_t)q);
        float4 ta = t4[0], tb = t4[1], tc = t4[2];
        {
            float r = (ta.x + 1.0f) * c1, g = (ta.y + 1.0f) * c1, bb = (ta.z + 1.0f) * c1;
            atomicAdd(&ht[bin_of(r * 0.299f + g * 0.587f + bb * 0.114f)], 1);
        }
        {
            float r = (ta.w + 1.0f) * c1, g = (tb.x + 1.0f) * c1, bb = (tb.y + 1.0f) * c1;
            atomicAdd(&ht[bin_of(r * 0.299f + g * 0.587f + bb * 0.114f)], 1);
        }
        {
            float r = (tb.z + 1.0f) * c1, g = (tb.w + 1.0f) * c1, bb = (tc.x + 1.0f) * c1;
            atomicAdd(&ht[bin_of(r * 0.299f + g * 0.587f + bb * 0.114f)], 1);
        }
        {
            float r = (tc.y + 1.0f) * c1, g = (tc.z + 1.0f) * c1, bb = (tc.w + 1.0f) * c1;
            atomicAdd(&ht[bin_of(r * 0.299f + g * 0.587f + bb * 0.114f)], 1);
        }
    }
    __syncthreads();

    // flush to global (hist pre-zeroed by tiny memset node)
    atomicAdd(&hist[t], hs[t]);
    atomicAdd(&hist[NBINS + t], ht[t]);
    __syncthreads();   // waits all this block's atomics (vmcnt drain at barrier)

    if (t == 0) {
        int old = __hip_atomic_fetch_add(counter, 1, __ATOMIC_ACQ_REL,
                                         __HIP_MEMORY_SCOPE_AGENT);
        lastFlag = (old == (int)gridDim.x - 1);
    }
    __syncthreads();
    if (!lastFlag) return;

    // ---- last block only: totals are final & published; do cdf + interp ----
    hs[t] = __hip_atomic_load(&hist[t], __ATOMIC_ACQUIRE, __HIP_MEMORY_SCOPE_AGENT);
    ht[t] = __hip_atomic_load(&hist[NBINS + t], __ATOMIC_ACQUIRE, __HIP_MEMORY_SCOPE_AGENT);
    __syncthreads();

    // Hillis-Steele inclusive scan over 256 bins
    for (int off = 1; off < NBINS; off <<= 1) {
        int aS = (t >= off) ? hs[t - off] : 0;
        int aT = (t >= off) ? ht[t - off] : 0;
        __syncthreads();
        hs[t] += aS; ht[t] += aT;
        __syncthreads();
    }
    int minS = hs[0], minT = ht[0];          // cdf_min == cdf[0] (nondecreasing)
    float denomN = (float)(4 * nquad - 1);
    float xS = (float)(hs[t] - minS) / denomN;   // cdfsrc[t]
    cdfT[t]  = (float)(ht[t] - minT) / denomN;   // cdftgt[t]
    __syncthreads();

    // interpolate(dx=cdftgt, dy=floating_space, x=cdfsrc[t])
    float res;
    if (xS <= cdfT[0]) {
        res = fs_val(0);
    } else if (xS >= cdfT[NBINS - 1]) {
        res = fs_val(NBINS - 1);
    } else {
        // first j with cdfT[j] > xS ; here cdfT[0] < xS < cdfT[255]
        int lo = 0, hi = NBINS - 1;
        while (hi - lo > 1) {
            int mid = (lo + hi) >> 1;
            if (cdfT[mid] > xS) hi = mid; else lo = mid;
        }
        int j1 = hi, j0 = hi - 1;
        float dx0 = cdfT[j0], dx1 = cdfT[j1];
        float dy0 = fs_val(j0), dy1 = fs_val(j1);
        res = dy0 + (dy1 - dy0) * (xS - dx0) / (dx1 - dx0);  // dx1 > xS >= dx0
    }
    pxmap[t] = res;   // plain store; kernel boundary publishes to kernel 2
}

// Kernel 2: per-pixel mapping through pxmap on the uniform grid.
__global__ void __launch_bounds__(TPB)
hm_apply(const float* __restrict__ src,
         const float* __restrict__ pxmap,
         float* __restrict__ out, int nquad) {
    __shared__ float pm[NBINS];
    pm[threadIdx.x] = pxmap[threadIdx.x];
    __syncthreads();

    const float c1 = (float)(127.0 / 255.0);
    const float c2 = (float)(255.0 / 127.0);
    int tid = blockIdx.x * TPB + threadIdx.x;
    int stride = gridDim.x * TPB;

    for (int q = tid; q < nquad; q += stride) {
        const float4* s4 = (const float4*)(src + 12 * (size_t)q);
        float4 a = s4[0], b = s4[1], c = s4[2];
        float xv[4] = {a.x, a.w, b.z, c.y};
        float ov[4];
        #pragma unroll
        for (int k = 0; k < 4; ++k) {
            float x = (xv[k] + 1.0f) * c1;
            float r;
            if (x <= 0.0f) {
                r = pm[0];
            } else if (x >= 1.0f) {
                r = pm[NBINS - 1];
            } else {
                // first j with fs[j] > x : guess + fixup to match exact float compares
                int g = (int)(x * 255.0f) + 1;
                g = g < 1 ? 1 : (g > NBINS - 1 ? NBINS - 1 : g);
                while (g < NBINS - 1 && fs_val(g) <= x) ++g;
                while (g > 1 && fs_val(g - 1) > x) --g;
                int j1 = g, j0 = g - 1;
                float dx0 = fs_val(j0), dx1 = fs_val(j1);
                r = pm[j0] + (pm[j1] - pm[j0]) * (x - dx0) / (dx1 - dx0);
            }
            r = r < 0.0f ? 0.0f : (r > 1.0f ? 1.0f : r);
            ov[k] = r * c2 - 1.0f;
        }
        float4 o;
        o.x = ov[0]; o.y = ov[1]; o.z = ov[2]; o.w = ov[3];
        ((float4*)out)[q] = o;
    }
}

extern "C" void kernel_launch(void* const* d_in, const int* in_sizes, int n_in,
                              void* d_out, int out_size, void* d_ws, size_t ws_size,
                              hipStream_t stream) {
    const float* src = (const float*)d_in[0];
    const float* tgt = (const float*)d_in[1];
    float* out = (float*)d_out;

    int nquad = out_size >> 2;        // 1024*1024/4

    int* hist = (int*)d_ws;                 // 512 ints
    int* counter = hist + 2 * NBINS;        // 1 int
    float* pxmap = (float*)(counter + 4);   // 256 floats (16B-aligned)

    // zero hist + counter (ws is poisoned 0xAA before every call)
    hipMemsetAsync(d_ws, 0, (2 * NBINS + 4) * sizeof(int), stream);

    hm_hist_cdf<<<HBLK, TPB, 0, stream>>>(src, tgt, hist, counter, pxmap, nquad);
    hm_apply<<<HBLK, TPB, 0, stream>>>(src, pxmap, out, nquad);
}

// Round 5
// 88.194 us; speedup vs baseline: 2.4694x; 1.0437x over previous
//
#include <hip/hip_runtime.h>

#define NBINS 256
#define HBLK  512   // 2 blocks per CU
#define TPB   256

__device__ __forceinline__ float fs_val(int j) {
    // floating_space[j] = clip(float32(j) * float32(1/255), 0, 1)
    const float c = (float)(1.0 / 255.0);
    float v = (float)j * c;
    return v > 1.0f ? 1.0f : v;
}

__device__ __forceinline__ int bin_of(float s) {
    int i = (int)(s * 256.0f);           // truncation toward zero, s >= 0
    i = i < 0 ? 0 : i;
    i = i > NBINS - 1 ? NBINS - 1 : i;
    return i;
}

// Kernel 1: both histograms in LDS, flushed with plain device-scope atomics.
__global__ void __launch_bounds__(TPB)
hm_hist(const float* __restrict__ src, const float* __restrict__ tgt,
        int* __restrict__ hist /* 512 ints, pre-zeroed */, int nquad) {
    __shared__ int hs[NBINS];
    __shared__ int ht[NBINS];
    const int t = threadIdx.x;               // TPB == NBINS
    hs[t] = 0; ht[t] = 0;
    __syncthreads();

    const float c1 = (float)(127.0 / 255.0);
    int tid = blockIdx.x * TPB + t;
    int stride = gridDim.x * TPB;

    for (int q = tid; q < nquad; q += stride) {
        const float4* s4 = (const float4*)(src + 12 * (size_t)q);
        float4 a = s4[0], b = s4[1], c = s4[2];
        // channel-0 of the 4 pixels: offsets 0,3,6,9
        atomicAdd(&hs[bin_of((a.x + 1.0f) * c1)], 1);
        atomicAdd(&hs[bin_of((a.w + 1.0f) * c1)], 1);
        atomicAdd(&hs[bin_of((b.z + 1.0f) * c1)], 1);
        atomicAdd(&hs[bin_of((c.y + 1.0f) * c1)], 1);

        const float4* t4 = (const float4*)(tgt + 12 * (size_t)q);
        float4 ta = t4[0], tb = t4[1], tc = t4[2];
        {
            float r = (ta.x + 1.0f) * c1, g = (ta.y + 1.0f) * c1, bb = (ta.z + 1.0f) * c1;
            atomicAdd(&ht[bin_of(r * 0.299f + g * 0.587f + bb * 0.114f)], 1);
        }
        {
            float r = (ta.w + 1.0f) * c1, g = (tb.x + 1.0f) * c1, bb = (tb.y + 1.0f) * c1;
            atomicAdd(&ht[bin_of(r * 0.299f + g * 0.587f + bb * 0.114f)], 1);
        }
        {
            float r = (tb.z + 1.0f) * c1, g = (tb.w + 1.0f) * c1, bb = (tc.x + 1.0f) * c1;
            atomicAdd(&ht[bin_of(r * 0.299f + g * 0.587f + bb * 0.114f)], 1);
        }
        {
            float r = (tc.y + 1.0f) * c1, g = (tc.z + 1.0f) * c1, bb = (tc.w + 1.0f) * c1;
            atomicAdd(&ht[bin_of(r * 0.299f + g * 0.587f + bb * 0.114f)], 1);
        }
    }
    __syncthreads();
    atomicAdd(&hist[t], hs[t]);
    atomicAdd(&hist[NBINS + t], ht[t]);
}

// Kernel 2: every block redundantly computes cdf + pxmap from the 2 KB hist
// (L2-hit), then maps its share of pixels. Kernel boundary publishes hist.
__global__ void __launch_bounds__(TPB)
hm_apply(const float* __restrict__ src, const int* __restrict__ hist,
         float* __restrict__ out, int nquad) {
    __shared__ int hs[NBINS];
    __shared__ int ht[NBINS];
    __shared__ float cdfT[NBINS];
    __shared__ float pm[NBINS];

    const int t = threadIdx.x;               // TPB == NBINS
    hs[t] = hist[t];
    ht[t] = hist[NBINS + t];
    __syncthreads();

    // Hillis-Steele inclusive scan over 256 bins
    for (int off = 1; off < NBINS; off <<= 1) {
        int aS = (t >= off) ? hs[t - off] : 0;
        int aT = (t >= off) ? ht[t - off] : 0;
        __syncthreads();
        hs[t] += aS; ht[t] += aT;
        __syncthreads();
    }
    int minS = hs[0], minT = ht[0];          // cdf_min == cdf[0] (nondecreasing)
    float denomN = (float)(4 * nquad - 1);
    float xS = (float)(hs[t] - minS) / denomN;   // cdfsrc[t]
    cdfT[t]  = (float)(ht[t] - minT) / denomN;   // cdftgt[t]
    __syncthreads();

    // interpolate(dx=cdftgt, dy=floating_space, x=cdfsrc[t]) -> pm[t]
    {
        float res;
        if (xS <= cdfT[0]) {
            res = fs_val(0);
        } else if (xS >= cdfT[NBINS - 1]) {
            res = fs_val(NBINS - 1);
        } else {
            // first j with cdfT[j] > xS ; here cdfT[0] < xS < cdfT[255]
            int lo = 0, hi = NBINS - 1;
            while (hi - lo > 1) {
                int mid = (lo + hi) >> 1;
                if (cdfT[mid] > xS) hi = mid; else lo = mid;
            }
            int j1 = hi, j0 = hi - 1;
            float dx0 = cdfT[j0], dx1 = cdfT[j1];
            float dy0 = fs_val(j0), dy1 = fs_val(j1);
            res = dy0 + (dy1 - dy0) * (xS - dx0) / (dx1 - dx0);  // dx1 > xS >= dx0
        }
        pm[t] = res;
    }
    __syncthreads();

    // map pixels through pm on the uniform grid
    const float c1 = (float)(127.0 / 255.0);
    const float c2 = (float)(255.0 / 127.0);
    int tid = blockIdx.x * TPB + t;
    int stride = gridDim.x * TPB;

    for (int q = tid; q < nquad; q += stride) {
        const float4* s4 = (const float4*)(src + 12 * (size_t)q);
        float4 a = s4[0], b = s4[1], c = s4[2];
        float xv[4] = {a.x, a.w, b.z, c.y};
        float ov[4];
        #pragma unroll
        for (int k = 0; k < 4; ++k) {
            float x = (xv[k] + 1.0f) * c1;
            float r;
            if (x <= 0.0f) {
                r = pm[0];
            } else if (x >= 1.0f) {
                r = pm[NBINS - 1];
            } else {
                // first j with fs[j] > x : guess + fixup to match exact float compares
                int g = (int)(x * 255.0f) + 1;
                g = g < 1 ? 1 : (g > NBINS - 1 ? NBINS - 1 : g);
                while (g < NBINS - 1 && fs_val(g) <= x) ++g;
                while (g > 1 && fs_val(g - 1) > x) --g;
                int j1 = g, j0 = g - 1;
                float dx0 = fs_val(j0), dx1 = fs_val(j1);
                r = pm[j0] + (pm[j1] - pm[j0]) * (x - dx0) / (dx1 - dx0);
            }
            r = r < 0.0f ? 0.0f : (r > 1.0f ? 1.0f : r);
            ov[k] = r * c2 - 1.0f;
        }
        float4 o;
        o.x = ov[0]; o.y = ov[1]; o.z = ov[2]; o.w = ov[3];
        ((float4*)out)[q] = o;
    }
}

extern "C" void kernel_launch(void* const* d_in, const int* in_sizes, int n_in,
                              void* d_out, int out_size, void* d_ws, size_t ws_size,
                              hipStream_t stream) {
    const float* src = (const float*)d_in[0];
    const float* tgt = (const float*)d_in[1];
    float* out = (float*)d_out;

    int nquad = out_size >> 2;        // 1024*1024/4
    int* hist = (int*)d_ws;           // 512 ints

    // zero hist (ws is re-poisoned to 0xAA before every call)
    hipMemsetAsync(d_ws, 0, 2 * NBINS * sizeof(int), stream);

    hm_hist<<<HBLK, TPB, 0, stream>>>(src, tgt, hist, nquad);
    hm_apply<<<HBLK, TPB, 0, stream>>>(src, hist, out, nquad);
}

// Round 6
// 85.855 us; speedup vs baseline: 2.5367x; 1.0272x over previous
//
#include <hip/hip_runtime.h>

#define NBINS 256
#define HBLK  512   // 2 blocks per CU
#define TPB   256

__device__ __forceinline__ float fs_val(int j) {
    // floating_space[j] = clip(float32(j) * float32(1/255), 0, 1)
    const float c = (float)(1.0 / 255.0);
    float v = (float)j * c;
    return v > 1.0f ? 1.0f : v;
}

__device__ __forceinline__ int bin_of(float s) {
    int i = (int)(s * 256.0f);           // truncation toward zero, s >= 0
    i = i < 0 ? 0 : i;
    i = i > NBINS - 1 ? NBINS - 1 : i;
    return i;
}

// Kernel 1: both histograms in LDS; block 0 zeroes the global hist and
// release-publishes a ready flag; each block acquire-waits on the flag only
// at flush time (expected 0 spins: flush happens ~4us after kernel start).
// Also emits the rescaled channel-0 values as a dense float4 buffer for
// kernel 2 (4 MB instead of re-reading 12 MB of RGB).
__global__ void __launch_bounds__(TPB)
hm_hist(const float* __restrict__ src, const float* __restrict__ tgt,
        int* __restrict__ hist /* 512 ints */, int* __restrict__ ready,
        float4* __restrict__ xbuf, int nquad) {
    __shared__ int hs[NBINS];
    __shared__ int ht[NBINS];
    const int t = threadIdx.x;               // TPB == NBINS
    hs[t] = 0; ht[t] = 0;

    if (blockIdx.x == 0) {
        __hip_atomic_store(&hist[t],         0, __ATOMIC_RELAXED, __HIP_MEMORY_SCOPE_AGENT);
        __hip_atomic_store(&hist[NBINS + t], 0, __ATOMIC_RELAXED, __HIP_MEMORY_SCOPE_AGENT);
        __syncthreads();
        if (t == 0)
            __hip_atomic_store(ready, 1, __ATOMIC_RELEASE, __HIP_MEMORY_SCOPE_AGENT);
    } else {
        __syncthreads();
    }

    const float c1 = (float)(127.0 / 255.0);
    int tid = blockIdx.x * TPB + t;
    int stride = gridDim.x * TPB;

    for (int q = tid; q < nquad; q += stride) {
        const float4* s4 = (const float4*)(src + 12 * (size_t)q);
        float4 a = s4[0], b = s4[1], c = s4[2];
        // rescaled channel-0 of the 4 pixels: offsets 0,3,6,9
        float p0 = (a.x + 1.0f) * c1;
        float p1 = (a.w + 1.0f) * c1;
        float p2 = (b.z + 1.0f) * c1;
        float p3 = (c.y + 1.0f) * c1;
        xbuf[q] = make_float4(p0, p1, p2, p3);   // dense input for kernel 2
        atomicAdd(&hs[bin_of(p0)], 1);
        atomicAdd(&hs[bin_of(p1)], 1);
        atomicAdd(&hs[bin_of(p2)], 1);
        atomicAdd(&hs[bin_of(p3)], 1);

        const float4* t4 = (const float4*)(tgt + 12 * (size_t)q);
        float4 ta = t4[0], tb = t4[1], tc = t4[2];
        {
            float r = (ta.x + 1.0f) * c1, g = (ta.y + 1.0f) * c1, bb = (ta.z + 1.0f) * c1;
            atomicAdd(&ht[bin_of(r * 0.299f + g * 0.587f + bb * 0.114f)], 1);
        }
        {
            float r = (ta.w + 1.0f) * c1, g = (tb.x + 1.0f) * c1, bb = (tb.y + 1.0f) * c1;
            atomicAdd(&ht[bin_of(r * 0.299f + g * 0.587f + bb * 0.114f)], 1);
        }
        {
            float r = (tb.z + 1.0f) * c1, g = (tb.w + 1.0f) * c1, bb = (tc.x + 1.0f) * c1;
            atomicAdd(&ht[bin_of(r * 0.299f + g * 0.587f + bb * 0.114f)], 1);
        }
        {
            float r = (tc.y + 1.0f) * c1, g = (tc.z + 1.0f) * c1, bb = (tc.w + 1.0f) * c1;
            atomicAdd(&ht[bin_of(r * 0.299f + g * 0.587f + bb * 0.114f)], 1);
        }
    }
    __syncthreads();

    // wait (normally 0 iterations) until hist is zeroed, then flush
    if (t == 0) {
        while (__hip_atomic_load(ready, __ATOMIC_ACQUIRE, __HIP_MEMORY_SCOPE_AGENT) != 1) {
            __builtin_amdgcn_s_sleep(8);
        }
    }
    __syncthreads();
    atomicAdd(&hist[t], hs[t]);
    atomicAdd(&hist[NBINS + t], ht[t]);
}

// Kernel 2: every block redundantly computes cdf + pxmap from the 2 KB hist
// (L2-hit), then maps its share of pixels from the dense xbuf.
__global__ void __launch_bounds__(TPB)
hm_apply(const float4* __restrict__ xbuf, const int* __restrict__ hist,
         float* __restrict__ out, int nquad) {
    __shared__ int hs[NBINS];
    __shared__ int ht[NBINS];
    __shared__ float cdfT[NBINS];
    __shared__ float pm[NBINS];

    const int t = threadIdx.x;               // TPB == NBINS
    hs[t] = hist[t];
    ht[t] = hist[NBINS + t];
    __syncthreads();

    // Hillis-Steele inclusive scan over 256 bins
    for (int off = 1; off < NBINS; off <<= 1) {
        int aS = (t >= off) ? hs[t - off] : 0;
        int aT = (t >= off) ? ht[t - off] : 0;
        __syncthreads();
        hs[t] += aS; ht[t] += aT;
        __syncthreads();
    }
    int minS = hs[0], minT = ht[0];          // cdf_min == cdf[0] (nondecreasing)
    float denomN = (float)(4 * nquad - 1);
    float xS = (float)(hs[t] - minS) / denomN;   // cdfsrc[t]
    cdfT[t]  = (float)(ht[t] - minT) / denomN;   // cdftgt[t]
    __syncthreads();

    // interpolate(dx=cdftgt, dy=floating_space, x=cdfsrc[t]) -> pm[t]
    {
        float res;
        if (xS <= cdfT[0]) {
            res = fs_val(0);
        } else if (xS >= cdfT[NBINS - 1]) {
            res = fs_val(NBINS - 1);
        } else {
            // first j with cdfT[j] > xS ; here cdfT[0] < xS < cdfT[255]
            int lo = 0, hi = NBINS - 1;
            while (hi - lo > 1) {
                int mid = (lo + hi) >> 1;
                if (cdfT[mid] > xS) hi = mid; else lo = mid;
            }
            int j1 = hi, j0 = hi - 1;
            float dx0 = cdfT[j0], dx1 = cdfT[j1];
            float dy0 = fs_val(j0), dy1 = fs_val(j1);
            res = dy0 + (dy1 - dy0) * (xS - dx0) / (dx1 - dx0);  // dx1 > xS >= dx0
        }
        pm[t] = res;
    }
    __syncthreads();

    // map pixels: xbuf already holds rescaled x in [0, ~1]
    const float c2 = (float)(255.0 / 127.0);
    int tid = blockIdx.x * TPB + t;
    int stride = gridDim.x * TPB;

    for (int q = tid; q < nquad; q += stride) {
        float4 xq = xbuf[q];
        float xv[4] = {xq.x, xq.y, xq.z, xq.w};
        float ov[4];
        #pragma unroll
        for (int k = 0; k < 4; ++k) {
            float x = xv[k];
            float r;
            if (x <= 0.0f) {
                r = pm[0];
            } else if (x >= 1.0f) {
                r = pm[NBINS - 1];
            } else {
                // first j with fs[j] > x : guess + fixup to match exact float compares
                int g = (int)(x * 255.0f) + 1;
                g = g < 1 ? 1 : (g > NBINS - 1 ? NBINS - 1 : g);
                while (g < NBINS - 1 && fs_val(g) <= x) ++g;
                while (g > 1 && fs_val(g - 1) > x) --g;
                int j1 = g, j0 = g - 1;
                float dx0 = fs_val(j0), dx1 = fs_val(j1);
                r = pm[j0] + (pm[j1] - pm[j0]) * (x - dx0) / (dx1 - dx0);
            }
            r = r < 0.0f ? 0.0f : (r > 1.0f ? 1.0f : r);
            ov[k] = r * c2 - 1.0f;
        }
        float4 o;
        o.x = ov[0]; o.y = ov[1]; o.z = ov[2]; o.w = ov[3];
        ((float4*)out)[q] = o;
    }
}

extern "C" void kernel_launch(void* const* d_in, const int* in_sizes, int n_in,
                              void* d_out, int out_size, void* d_ws, size_t ws_size,
                              hipStream_t stream) {
    const float* src = (const float*)d_in[0];
    const float* tgt = (const float*)d_in[1];
    float* out = (float*)d_out;

    int nquad = out_size >> 2;        // 1024*1024/4

    char* ws = (char*)d_ws;
    int* hist = (int*)ws;                     // 512 ints @ 0
    int* ready = (int*)(ws + 2048);           // 1 int  @ 2048 (poison 0xAA.. != 1)
    float4* xbuf = (float4*)(ws + 4096);      // 4 MB   @ 4096

    hm_hist<<<HBLK, TPB, 0, stream>>>(src, tgt, hist, ready, xbuf, nquad);
    hm_apply<<<HBLK, TPB, 0, stream>>>(xbuf, hist, out, nquad);
}